// Round 3
// baseline (564.066 us; speedup 1.0000x reference)
//
#include <hip/hip_runtime.h>
#include <math.h>
#include <stdint.h>

// ---------------------------------------------------------------------------
// MultiHeadAttention, softmax over HEAD axis (dim=1), bf16 MFMA pipeline.
// B=4, S=2048, DIM=1024, H=8, DH=128.
//   q = (Q WQ^T) * 1/sqrt(128)   [b,s,1024] bf16 (scale folded in epilogue)
//   k =  K WK^T                  [b,s,1024] bf16
//   vt = (V WV^T) transposed ->  [b,h,dh,s] bf16 (epilogue transpose)
//   FUSED attention (v6): softmax over heads -> den[q,k]=sum_h e_h[q,k] is
//   elementwise-local; no P materialization, QK computed once.
//   v6 adds deep register prefetch (T14): K frags for iter t+1 issued right
//   after iter t's QK MFMAs (consumed ~1500cy later, across both barriers);
//   V kc=0 half hoisted over the exchange; s_setprio around MFMA clusters.
//   qkv_proj/gemm_bt: XCD-aware remap so the 8 blocks sharing an A row-panel
//   land on one XCD (A panel L2-resident -> FETCH 200MB -> ~70MB).
// ---------------------------------------------------------------------------

typedef __attribute__((ext_vector_type(8))) __bf16 bf16x8;
typedef __attribute__((ext_vector_type(4))) __bf16 bf16x4;
typedef __attribute__((ext_vector_type(4))) float  f32x4;

__device__ __forceinline__ f32x4 mfma16(bf16x8 a, bf16x8 b, f32x4 c) {
    return __builtin_amdgcn_mfma_f32_16x16x32_bf16(a, b, c, 0, 0, 0);
}

// async global->LDS, 16B per lane; LDS dest must be wave-uniform-base + lane*16
__device__ __forceinline__ void cp16(void* lds, const void* g) {
    __builtin_amdgcn_global_load_lds(
        (__attribute__((address_space(1))) void*)(void*)(const_cast<void*>(g)),
        (__attribute__((address_space(3))) void*)lds,
        16, 0, 0);
}

// ---------------------------------------------------------------------------
// 4 weight tensors in one launch
__global__ void cast4_f32_to_bf16(const float* __restrict__ s0, __bf16* __restrict__ d0,
                                  const float* __restrict__ s1, __bf16* __restrict__ d1,
                                  const float* __restrict__ s2, __bf16* __restrict__ d2,
                                  const float* __restrict__ s3, __bf16* __restrict__ d3,
                                  int n4) {
    const float* s = (blockIdx.y == 0) ? s0 : (blockIdx.y == 1) ? s1
                    : (blockIdx.y == 2) ? s2 : s3;
    __bf16* d = (blockIdx.y == 0) ? d0 : (blockIdx.y == 1) ? d1
               : (blockIdx.y == 2) ? d2 : d3;
    int i = blockIdx.x * blockDim.x + threadIdx.x;
    const int stride = gridDim.x * blockDim.x;
    for (; i < n4; i += stride) {
        float4 f = ((const float4*)s)[i];
        bf16x4 o;
        o[0] = (__bf16)f.x; o[1] = (__bf16)f.y; o[2] = (__bf16)f.z; o[3] = (__bf16)f.w;
        ((bf16x4*)d)[i] = o;
    }
}

// Q, K, V activations in one launch (y selects tensor)
__global__ void cast3_f32_to_bf16(const float* __restrict__ s0, __bf16* __restrict__ d0,
                                  const float* __restrict__ s1, __bf16* __restrict__ d1,
                                  const float* __restrict__ s2, __bf16* __restrict__ d2,
                                  int n4) {
    const float* s = (blockIdx.y == 0) ? s0 : (blockIdx.y == 1) ? s1 : s2;
    __bf16* d = (blockIdx.y == 0) ? d0 : (blockIdx.y == 1) ? d1 : d2;
    int i = blockIdx.x * blockDim.x + threadIdx.x;
    const int stride = gridDim.x * blockDim.x;
    for (; i < n4; i += stride) {
        float4 f = ((const float4*)s)[i];
        bf16x4 o;
        o[0] = (__bf16)f.x; o[1] = (__bf16)f.y; o[2] = (__bf16)f.z; o[3] = (__bf16)f.w;
        ((bf16x4*)d)[i] = o;
    }
}

// ---------------------------------------------------------------------------
// C[8192,1024] = A[8192,1024] * Bt[1024,1024]^T   (Bt stored [N,K] row-major)
// MODE 1: f32 out, natural [m,n]  (used for the final WO projection)
// XCD remap: consecutive dispatch ids take consecutive ROW panels so each
// A panel is read by exactly one XCD (L2-resident).
template<int MODE>
__global__ __launch_bounds__(256, 2) void gemm_bt(const __bf16* __restrict__ A,
                                                  const __bf16* __restrict__ Bt,
                                                  void* __restrict__ out,
                                                  float scale)
{
    __shared__ __bf16 As[128 * 32];
    __shared__ __bf16 Bs[128 * 32];
    const int tid  = threadIdx.x;
    const int lane = tid & 63;
    const int u = lane >> 4, v = lane & 15;
    const int w = tid >> 6;
    const int wm = (w >> 1) * 64, wn = (w & 1) * 64;
    const int bid = blockIdx.y * 8 + blockIdx.x;   // dispatch-linear
    const long tM = (long)(bid & 63) * 128;        // row panel (XCD = bid&7)
    const int  tN = (bid >> 6) * 128;              // col panel

    f32x4 acc[4][4];
#pragma unroll
    for (int i = 0; i < 4; ++i)
#pragma unroll
        for (int j = 0; j < 4; ++j) acc[i][j] = (f32x4){0.f, 0.f, 0.f, 0.f};

    const int c0 = tid, c1 = tid + 256;
    const int ar0 = c0 >> 2, ak0 = (c0 & 3) * 8;
    const int ar1 = c1 >> 2, ak1 = (c1 & 3) * 8;

    const __bf16* Ab = A  + tM * 1024;
    const __bf16* Bb = Bt + (long)tN * 1024;

    for (int k0 = 0; k0 < 1024; k0 += 32) {
        __syncthreads();
        cp16(&As[ar0 * 32 + ak0], Ab + (long)ar0 * 1024 + k0 + ak0);
        cp16(&As[ar1 * 32 + ak1], Ab + (long)ar1 * 1024 + k0 + ak1);
        cp16(&Bs[ar0 * 32 + ak0], Bb + (long)ar0 * 1024 + k0 + ak0);
        cp16(&Bs[ar1 * 32 + ak1], Bb + (long)ar1 * 1024 + k0 + ak1);
        __syncthreads();

        bf16x8 af[4], bfr[4];
#pragma unroll
        for (int i = 0; i < 4; ++i)
            af[i] = *(const bf16x8*)&As[(wm + i * 16 + v) * 32 + u * 8];
#pragma unroll
        for (int j = 0; j < 4; ++j)
            bfr[j] = *(const bf16x8*)&Bs[(wn + j * 16 + v) * 32 + u * 8];
#pragma unroll
        for (int i = 0; i < 4; ++i)
#pragma unroll
            for (int j = 0; j < 4; ++j)
                acc[i][j] = mfma16(af[i], bfr[j], acc[i][j]);
    }

#pragma unroll
    for (int i = 0; i < 4; ++i) {
#pragma unroll
        for (int j = 0; j < 4; ++j) {
            const long row0 = tM + wm + i * 16 + u * 4;
            const int  col  = tN + wn + j * 16 + v;
            if (MODE == 1) {
                float* o = (float*)out;
#pragma unroll
                for (int r = 0; r < 4; ++r)
                    o[(row0 + r) * 1024 + col] = acc[i][j][r];
            } else {
                __bf16* o = (__bf16*)out;
#pragma unroll
                for (int r = 0; r < 4; ++r)
                    o[(row0 + r) * 1024 + col] = (__bf16)(acc[i][j][r] * scale);
            }
        }
    }
}

// ---------------------------------------------------------------------------
// Batched Q/K/V projection: grid.z selects (A, Bt, out, mode).
// z=0: qp = (Xq WQ^T)*qscale   (natural bf16)
// z=1: kp =  Xk WK^T           (natural bf16)
// z=2: vt =  Xv WV^T           v-transposed [b,h,dh,s] bf16
// XCD remap as gemm_bt.
__global__ __launch_bounds__(256, 2) void qkv_proj(
    const __bf16* __restrict__ xq, const __bf16* __restrict__ xk,
    const __bf16* __restrict__ xv,
    const __bf16* __restrict__ wq, const __bf16* __restrict__ wk,
    const __bf16* __restrict__ wv,
    __bf16* __restrict__ qp, __bf16* __restrict__ kp, __bf16* __restrict__ vtb,
    float qscale)
{
    __shared__ __bf16 As[128 * 32];
    __shared__ __bf16 Bs[128 * 32];
    const int z = blockIdx.z;
    const __bf16* A  = (z == 0) ? xq : (z == 1) ? xk : xv;
    const __bf16* Bt = (z == 0) ? wq : (z == 1) ? wk : wv;
    __bf16* out      = (z == 0) ? qp : (z == 1) ? kp : vtb;
    const float scale = (z == 0) ? qscale : 1.0f;

    const int tid  = threadIdx.x;
    const int lane = tid & 63;
    const int u = lane >> 4, v = lane & 15;
    const int w = tid >> 6;
    const int wm = (w >> 1) * 64, wn = (w & 1) * 64;
    const int bid = blockIdx.y * 8 + blockIdx.x;   // dispatch-linear within z
    const long tM = (long)(bid & 63) * 128;        // row panel (XCD = bid&7)
    const int  tN = (bid >> 6) * 128;              // col panel

    f32x4 acc[4][4];
#pragma unroll
    for (int i = 0; i < 4; ++i)
#pragma unroll
        for (int j = 0; j < 4; ++j) acc[i][j] = (f32x4){0.f, 0.f, 0.f, 0.f};

    const int c0 = tid, c1 = tid + 256;
    const int ar0 = c0 >> 2, ak0 = (c0 & 3) * 8;
    const int ar1 = c1 >> 2, ak1 = (c1 & 3) * 8;

    const __bf16* Ab = A  + tM * 1024;
    const __bf16* Bb = Bt + (long)tN * 1024;

    for (int k0 = 0; k0 < 1024; k0 += 32) {
        __syncthreads();
        cp16(&As[ar0 * 32 + ak0], Ab + (long)ar0 * 1024 + k0 + ak0);
        cp16(&As[ar1 * 32 + ak1], Ab + (long)ar1 * 1024 + k0 + ak1);
        cp16(&Bs[ar0 * 32 + ak0], Bb + (long)ar0 * 1024 + k0 + ak0);
        cp16(&Bs[ar1 * 32 + ak1], Bb + (long)ar1 * 1024 + k0 + ak1);
        __syncthreads();

        bf16x8 af[4], bfr[4];
#pragma unroll
        for (int i = 0; i < 4; ++i)
            af[i] = *(const bf16x8*)&As[(wm + i * 16 + v) * 32 + u * 8];
#pragma unroll
        for (int j = 0; j < 4; ++j)
            bfr[j] = *(const bf16x8*)&Bs[(wn + j * 16 + v) * 32 + u * 8];
#pragma unroll
        for (int i = 0; i < 4; ++i)
#pragma unroll
            for (int j = 0; j < 4; ++j)
                acc[i][j] = mfma16(af[i], bfr[j], acc[i][j]);
    }

#pragma unroll
    for (int i = 0; i < 4; ++i) {
#pragma unroll
        for (int j = 0; j < 4; ++j) {
            const long row0 = tM + wm + i * 16 + u * 4;
            const int  col  = tN + wn + j * 16 + v;
            if (z < 2) {
#pragma unroll
                for (int r = 0; r < 4; ++r)
                    out[(row0 + r) * 1024 + col] = (__bf16)(acc[i][j][r] * scale);
            } else {
                const int bidx = (int)(row0 >> 11);
                const int s    = (int)(row0 & 2047);          // 4-aligned
                const int h = col >> 7, dh = col & 127;
                bf16x4 pk;
#pragma unroll
                for (int r = 0; r < 4; ++r) pk[r] = (__bf16)acc[i][j][r];
                *(bf16x4*)&out[((long)(bidx * 8 + h) * 128 + dh) * 2048 + s] = pk;
            }
        }
    }
}

// ---------------------------------------------------------------------------
// fused_attn v6: QK^T -> head-softmax -> PV, one kernel.
// Grid 256 blocks (64 q-tiles x 4 b, XCD-clustered), 512 threads = 8 waves,
// wave w == head w. q-tile = 32 (2 qj), KT = 64 keys/iter, 32 iters.
// Per iter:
//   QK: e[ki][qj] from REGISTER-RESIDENT kf (loaded during prior iter) x qf.
//   prefetch: next iter's 16 K frags issued immediately after QK MFMAs
//     (program order guarantees post-QK issue; consumed after 2 barriers).
//   exp -> dbuf exchange (2 barriers) -> P to wave-private swizzled Pl ->
//   PV (vf0 hoisted over exchange; vf1 inline).
// LDS: dbuf 64K + rbuf 8K + Pl 32K = 104 KB -> 1 block/CU, 8 waves.
// VGPR ~230/256: ctx 64 + qf 32 + kf 64 + vf0 32 + e 32 + temps.
__global__ __launch_bounds__(512, 2) void fused_attn(
    const __bf16* __restrict__ qp, const __bf16* __restrict__ kp,
    const __bf16* __restrict__ vt, __bf16* __restrict__ ctx)
{
    __shared__ f32x4 dbuf[8][8][64];   // 64 KB  e-partials [wave][group][lane]
    __shared__ f32x4 rbuf[8][64];      // 8 KB   rinv per group [group][lane]
    __shared__ __bf16 Pl[8][32][64];   // 32 KB  wave-private P [q][k] swizzled

    const int tid  = threadIdx.x;
    const int w    = tid >> 6;          // wave == head
    const int lane = tid & 63;
    const int u = lane >> 4, v = lane & 15;

    // block -> (qt, b), clustered so XCD (bid%8) serves a single batch b
    const int g0 = blockIdx.x;
    const int xs = g0 & 7, idx = g0 >> 3;
    const int b  = xs >> 1;
    const int qt = idx * 2 + (xs & 1);
    const int q0 = qt * 32;
    const int h  = w;

    const __bf16* Qb = qp + ((long)b * 2048 + q0) * 1024 + h * 128;
    const __bf16* Kb = kp + (long)b * 2048 * 1024 + h * 128;
    const __bf16* Vb = vt + (long)(b * 8 + h) * 128 * 2048;

    // Q fragments resident in registers (32 VGPR)
    bf16x8 qf[2][4];
#pragma unroll
    for (int qj = 0; qj < 2; ++qj)
#pragma unroll
        for (int kk = 0; kk < 4; ++kk)
            qf[qj][kk] = *(const bf16x8*)&Qb[(long)(qj * 16 + v) * 1024 + kk * 32 + u * 8];

    f32x4 ctxa[8][2];
#pragma unroll
    for (int dt = 0; dt < 8; ++dt)
#pragma unroll
        for (int qj = 0; qj < 2; ++qj) ctxa[dt][qj] = (f32x4){0.f, 0.f, 0.f, 0.f};

    // K prologue: frags for kt=0 (64 VGPR, live across backedge)
    bf16x8 kf[4][4];
#pragma unroll
    for (int ki = 0; ki < 4; ++ki)
#pragma unroll
        for (int kk = 0; kk < 4; ++kk)
            kf[ki][kk] = *(const bf16x8*)&Kb[(long)(ki * 16 + v) * 1024 + kk * 32 + u * 8];

    for (int kt = 0; kt < 2048; kt += 64) {
        const int ktn = (kt + 64) & 2047;   // last-iter prefetch wraps (unused)

        // ---- QK: s^T[k][q], pure-register MFMA cluster ----
        f32x4 e[4][2];
#pragma unroll
        for (int ki = 0; ki < 4; ++ki)
#pragma unroll
            for (int qj = 0; qj < 2; ++qj) e[ki][qj] = (f32x4){0.f, 0.f, 0.f, 0.f};

        __builtin_amdgcn_s_setprio(1);
#pragma unroll
        for (int ki = 0; ki < 4; ++ki)
#pragma unroll
            for (int qj = 0; qj < 2; ++qj)
#pragma unroll
                for (int kk = 0; kk < 4; ++kk)
                    e[ki][qj] = mfma16(kf[ki][kk], qf[qj][kk], e[ki][qj]);
        __builtin_amdgcn_s_setprio(0);

        // ---- prefetch next iter's K frags (WAR on kf keeps these post-QK;
        //      results consumed after both barriers -> ~1500cy window) ----
#pragma unroll
        for (int ki = 0; ki < 4; ++ki)
#pragma unroll
            for (int kk = 0; kk < 4; ++kk)
                kf[ki][kk] = *(const bf16x8*)&Kb[(long)(ktn + ki * 16 + v) * 1024
                                                 + kk * 32 + u * 8];

        // ---- exp in place ----
#pragma unroll
        for (int ki = 0; ki < 4; ++ki)
#pragma unroll
            for (int qj = 0; qj < 2; ++qj)
#pragma unroll
                for (int r = 0; r < 4; ++r)
                    e[ki][qj][r] = __expf(e[ki][qj][r]);

        // hoist PV kc=0 vt loads: latency hides under the exchange barriers
        bf16x8 vf0[8];
#pragma unroll
        for (int dt = 0; dt < 8; ++dt)
            vf0[dt] = *(const bf16x8*)&Vb[(long)(dt * 16 + v) * 2048 + kt + u * 8];

        // ---- den exchange ----
#pragma unroll
        for (int ki = 0; ki < 4; ++ki)
#pragma unroll
            for (int qj = 0; qj < 2; ++qj)
                dbuf[w][ki * 2 + qj][lane] = e[ki][qj];
        __syncthreads();

        // wave w sums group w over all 8 waves
        f32x4 d = dbuf[0][w][lane];
#pragma unroll
        for (int wp = 1; wp < 8; ++wp) {
            f32x4 t = dbuf[wp][w][lane];
#pragma unroll
            for (int r = 0; r < 4; ++r) d[r] += t[r];
        }
        f32x4 rv;
#pragma unroll
        for (int r = 0; r < 4; ++r) rv[r] = 1.0f / d[r];
        rbuf[w][lane] = rv;
        __syncthreads();

        // ---- normalize, write P to wave-private swizzled LDS ----
#pragma unroll
        for (int ki = 0; ki < 4; ++ki)
#pragma unroll
            for (int qj = 0; qj < 2; ++qj) {
                f32x4 rr = rbuf[ki * 2 + qj][lane];
                bf16x4 o;
#pragma unroll
                for (int r = 0; r < 4; ++r) o[r] = (__bf16)(e[ki][qj][r] * rr[r]);
                const int q  = qj * 16 + v;
                const int ch = (ki * 2 + (u >> 1)) ^ (v & 7);   // 16B-chunk swizzle
                *(bf16x4*)((char*)&Pl[w][q][0] + ch * 16 + (u & 1) * 8) = o;
            }

        // ---- PV (wave-private Pl: same-wave ds ordering, no barrier) ----
        bf16x8 pfr[2][2];
#pragma unroll
        for (int kc = 0; kc < 2; ++kc)
#pragma unroll
            for (int qj = 0; qj < 2; ++qj) {
                const int q  = qj * 16 + v;
                const int ch = (kc * 4 + u) ^ (v & 7);
                pfr[kc][qj] = *(const bf16x8*)((const char*)&Pl[w][q][0] + ch * 16);
            }
        __builtin_amdgcn_s_setprio(1);
#pragma unroll
        for (int dt = 0; dt < 8; ++dt) {
#pragma unroll
            for (int qj = 0; qj < 2; ++qj)
                ctxa[dt][qj] = mfma16(vf0[dt], pfr[0][qj], ctxa[dt][qj]);
            bf16x8 vf1 = *(const bf16x8*)&Vb[(long)(dt * 16 + v) * 2048 + kt + 32 + u * 8];
#pragma unroll
            for (int qj = 0; qj < 2; ++qj)
                ctxa[dt][qj] = mfma16(vf1, pfr[1][qj], ctxa[dt][qj]);
        }
        __builtin_amdgcn_s_setprio(0);
    }

    // ---- epilogue: concat layout [b][q][h*128+dh] ----
#pragma unroll
    for (int dt = 0; dt < 8; ++dt)
#pragma unroll
        for (int qj = 0; qj < 2; ++qj) {
            bf16x4 o;
#pragma unroll
            for (int r = 0; r < 4; ++r) o[r] = (__bf16)ctxa[dt][qj][r];
            *(bf16x4*)&ctx[((long)b * 2048 + q0 + qj * 16 + v) * 1024
                           + h * 128 + dt * 16 + u * 4] = o;
        }
}

// ---------------------------------------------------------------------------
extern "C" void kernel_launch(void* const* d_in, const int* in_sizes, int n_in,
                              void* d_out, int out_size, void* d_ws, size_t ws_size,
                              hipStream_t stream)
{
    const float* Q  = (const float*)d_in[0];
    const float* K  = (const float*)d_in[1];
    const float* V  = (const float*)d_in[2];
    const float* WQ = (const float*)d_in[3];
    const float* WK = (const float*)d_in[4];
    const float* WV = (const float*)d_in[5];
    const float* WO = (const float*)d_in[6];

    // workspace layout (bf16 elems): 4x 1M weights + 7x 8.4M tensors = 125.8 MB
    __bf16* ws = (__bf16*)d_ws;
    __bf16* wq = ws;
    __bf16* wk = wq + 1048576;
    __bf16* wv = wk + 1048576;
    __bf16* wo = wv + 1048576;
    __bf16* xq = wo + 1048576;     // Q cast
    __bf16* xk = xq + 8388608;     // K cast
    __bf16* xv = xk + 8388608;     // V cast
    __bf16* qp = xv + 8388608;
    __bf16* kp = qp + 8388608;
    __bf16* vt = kp + 8388608;
    __bf16* xb = vt + 8388608;     // ctx

    const float qscale = 0.08838834764831845f;   // 1/sqrt(128)

    cast4_f32_to_bf16<<<dim3(256, 4), 256, 0, stream>>>(
        WQ, wq, WK, wk, WV, wv, WO, wo, 262144);
    cast3_f32_to_bf16<<<dim3(2048, 3), 256, 0, stream>>>(
        Q, xq, K, xk, V, xv, 2097152);
    qkv_proj<<<dim3(8, 64, 3), 256, 0, stream>>>(
        xq, xk, xv, wq, wk, wv, qp, kp, vt, qscale);

    fused_attn<<<256, 512, 0, stream>>>(qp, kp, vt, xb);

    gemm_bt<1><<<dim3(8, 64), 256, 0, stream>>>(xb, wo, (float*)d_out, 1.0f);
}

// Round 5
// 535.586 us; speedup vs baseline: 1.0532x; 1.0532x over previous
//
#include <hip/hip_runtime.h>
#include <math.h>
#include <stdint.h>

// ---------------------------------------------------------------------------
// MultiHeadAttention, softmax over HEAD axis (dim=1), bf16 MFMA pipeline.
// B=4, S=2048, DIM=1024, H=8, DH=128.
//   qp = (Q WQ^T)*1/sqrt(128), kp = K WK^T   [b,s,1024] bf16
//   vt = (V WV^T)^T  [b,h,dh,s] bf16         (casts fused into GEMM staging)
//   fused_attn v8: softmax over heads -> den[q,k]=sum_h e_h[q,k] elementwise.
//     512 blocks (64 qt x 4 b x 2 k-halves), 8 waves = 8 heads, q-tile 32,
//     KT=64, 16 iters. LDS 40 KB (Pl 32K + rbuf 8K) -> 2 blocks/CU.
//     Pl doubles as BOTH the den-exchange buffer AND the PV operand tile:
//       write bf16(e) -> barrier -> reduce den from all 8 waves' Pl slices
//       -> rinv -> barrier -> RMW-normalize own Pl in place -> PV.
//     (round-2-verified Pl swizzle; the round-4 bpermute path is dead.)
//     ctx f32 partials (per k-half), summed in the WO GEMM's A-staging.
// ---------------------------------------------------------------------------

typedef __attribute__((ext_vector_type(8))) __bf16 bf16x8;
typedef __attribute__((ext_vector_type(4))) __bf16 bf16x4;
typedef __attribute__((ext_vector_type(4))) float  f32x4;
typedef __attribute__((ext_vector_type(2))) unsigned int u32x2;

__device__ __forceinline__ f32x4 mfma16(bf16x8 a, bf16x8 b, f32x4 c) {
    return __builtin_amdgcn_mfma_f32_16x16x32_bf16(a, b, c, 0, 0, 0);
}

// async global->LDS, 16B per lane; LDS dest must be wave-uniform-base + lane*16
__device__ __forceinline__ void cp16(void* lds, const void* g) {
    __builtin_amdgcn_global_load_lds(
        (__attribute__((address_space(1))) void*)(void*)(const_cast<void*>(g)),
        (__attribute__((address_space(3))) void*)lds,
        16, 0, 0);
}

// pack two f32 into a dword of two bf16 (RNE via HW cvt)
__device__ __forceinline__ uint32_t pk2(float a, float b) {
    __bf16 x = (__bf16)a, y = (__bf16)b;
    unsigned short xa = __builtin_bit_cast(unsigned short, x);
    unsigned short yb = __builtin_bit_cast(unsigned short, y);
    return (uint32_t)xa | ((uint32_t)yb << 16);
}
__device__ __forceinline__ float bflo(uint32_t d) {
    return __builtin_bit_cast(float, d << 16);
}
__device__ __forceinline__ float bfhi(uint32_t d) {
    return __builtin_bit_cast(float, d & 0xffff0000u);
}

// ---------------------------------------------------------------------------
// 4 weight tensors in one launch (bf16 for GEMM B-operands)
__global__ void cast4_f32_to_bf16(const float* __restrict__ s0, __bf16* __restrict__ d0,
                                  const float* __restrict__ s1, __bf16* __restrict__ d1,
                                  const float* __restrict__ s2, __bf16* __restrict__ d2,
                                  const float* __restrict__ s3, __bf16* __restrict__ d3,
                                  int n4) {
    const float* s = (blockIdx.y == 0) ? s0 : (blockIdx.y == 1) ? s1
                    : (blockIdx.y == 2) ? s2 : s3;
    __bf16* d = (blockIdx.y == 0) ? d0 : (blockIdx.y == 1) ? d1
               : (blockIdx.y == 2) ? d2 : d3;
    int i = blockIdx.x * blockDim.x + threadIdx.x;
    const int stride = gridDim.x * blockDim.x;
    for (; i < n4; i += stride) {
        float4 f = ((const float4*)s)[i];
        bf16x4 o;
        o[0] = (__bf16)f.x; o[1] = (__bf16)f.y; o[2] = (__bf16)f.z; o[3] = (__bf16)f.w;
        ((bf16x4*)d)[i] = o;
    }
}

// ---------------------------------------------------------------------------
// Batched Q/K/V projection with FUSED f32->bf16 cast in the A-staging.
// grid.z: 0 -> qp=(Q WQ^T)*qscale, 1 -> kp=K WK^T, 2 -> vt=(V WV^T)^T.
// XCD remap: consecutive dispatch ids take consecutive ROW panels.
__global__ __launch_bounds__(256, 2) void qkv_proj(
    const float* __restrict__ Qf, const float* __restrict__ Kf,
    const float* __restrict__ Vf,
    const __bf16* __restrict__ wq, const __bf16* __restrict__ wk,
    const __bf16* __restrict__ wv,
    __bf16* __restrict__ qp, __bf16* __restrict__ kp, __bf16* __restrict__ vtb,
    float qscale)
{
    __shared__ __bf16 As[128 * 32];
    __shared__ __bf16 Bs[128 * 32];
    const int z = blockIdx.z;
    const float*  Af = (z == 0) ? Qf : (z == 1) ? Kf : Vf;
    const __bf16* Bt = (z == 0) ? wq : (z == 1) ? wk : wv;
    __bf16* out      = (z == 0) ? qp : (z == 1) ? kp : vtb;
    const float scale = (z == 0) ? qscale : 1.0f;

    const int tid  = threadIdx.x;
    const int lane = tid & 63;
    const int u = lane >> 4, v = lane & 15;
    const int w = tid >> 6;
    const int wm = (w >> 1) * 64, wn = (w & 1) * 64;
    const int bid = blockIdx.y * 8 + blockIdx.x;
    const long tM = (long)(bid & 63) * 128;
    const int  tN = (bid >> 6) * 128;

    f32x4 acc[4][4];
#pragma unroll
    for (int i = 0; i < 4; ++i)
#pragma unroll
        for (int j = 0; j < 4; ++j) acc[i][j] = (f32x4){0.f, 0.f, 0.f, 0.f};

    const int ar0 = tid >> 2, ak0 = (tid & 3) * 8;
    const int ar1 = ar0 + 64;

    const float*  Ab = Af + tM * 1024;
    const __bf16* Bb = Bt + (long)tN * 1024;

    for (int k0 = 0; k0 < 1024; k0 += 32) {
        __syncthreads();
        // A: reg-staged f32 -> bf16 (fused cast)
        {
            const float* p = Ab + (long)ar0 * 1024 + k0 + ak0;
            float4 x0 = *(const float4*)p, x1 = *(const float4*)(p + 4);
            bf16x8 o;
            o[0] = (__bf16)x0.x; o[1] = (__bf16)x0.y; o[2] = (__bf16)x0.z; o[3] = (__bf16)x0.w;
            o[4] = (__bf16)x1.x; o[5] = (__bf16)x1.y; o[6] = (__bf16)x1.z; o[7] = (__bf16)x1.w;
            *(bf16x8*)&As[ar0 * 32 + ak0] = o;
            const float* q = Ab + (long)ar1 * 1024 + k0 + ak0;
            float4 y0 = *(const float4*)q, y1 = *(const float4*)(q + 4);
            bf16x8 o2;
            o2[0] = (__bf16)y0.x; o2[1] = (__bf16)y0.y; o2[2] = (__bf16)y0.z; o2[3] = (__bf16)y0.w;
            o2[4] = (__bf16)y1.x; o2[5] = (__bf16)y1.y; o2[6] = (__bf16)y1.z; o2[7] = (__bf16)y1.w;
            *(bf16x8*)&As[ar1 * 32 + ak0] = o2;
        }
        // B: async direct to LDS (bf16 weights)
        cp16(&Bs[ar0 * 32 + ak0], Bb + (long)ar0 * 1024 + k0 + ak0);
        cp16(&Bs[ar1 * 32 + ak0], Bb + (long)ar1 * 1024 + k0 + ak0);
        __syncthreads();

        bf16x8 af[4], bfr[4];
#pragma unroll
        for (int i = 0; i < 4; ++i)
            af[i] = *(const bf16x8*)&As[(wm + i * 16 + v) * 32 + u * 8];
#pragma unroll
        for (int j = 0; j < 4; ++j)
            bfr[j] = *(const bf16x8*)&Bs[(wn + j * 16 + v) * 32 + u * 8];
#pragma unroll
        for (int i = 0; i < 4; ++i)
#pragma unroll
            for (int j = 0; j < 4; ++j)
                acc[i][j] = mfma16(af[i], bfr[j], acc[i][j]);
    }

#pragma unroll
    for (int i = 0; i < 4; ++i) {
#pragma unroll
        for (int j = 0; j < 4; ++j) {
            const long row0 = tM + wm + i * 16 + u * 4;
            const int  col  = tN + wn + j * 16 + v;
            if (z < 2) {
#pragma unroll
                for (int r = 0; r < 4; ++r)
                    out[(row0 + r) * 1024 + col] = (__bf16)(acc[i][j][r] * scale);
            } else {
                const int bidx = (int)(row0 >> 11);
                const int s    = (int)(row0 & 2047);          // 4-aligned
                const int h = col >> 7, dh = col & 127;
                bf16x4 pkv;
#pragma unroll
                for (int r = 0; r < 4; ++r) pkv[r] = (__bf16)acc[i][j][r];
                *(bf16x4*)&out[((long)(bidx * 8 + h) * 128 + dh) * 2048 + s] = pkv;
            }
        }
    }
}

// ---------------------------------------------------------------------------
// fused_attn v8: QK^T -> head-softmax -> PV.
// 512 blocks: bid = qt*8 + b*2 + kh  (XCD = b*2+kh: K/V halves L2-resident).
// 512 threads = 8 waves, wave w == head. q-tile 32 (2 qj), KT=64, 16 iters
// over this block's k-half. ctx f32 partial -> ctxp + kh*8388608.
//
// Pl is exchange buffer + PV tile in one (wave-private slices Pl[w]):
//   step 1 per ki: 8 QK MFMA, exp, pk2 -> write UNNORMALIZED bf16(e) to
//     Pl[w] (round-2-verified chunk swizzle: ch=(ki*2+(u>>1))^(v&7)).
//   barrier. step 2: wave w reduces group w=(ki_w,qj_w): reads the same
//     8B slot from all 8 waves' Pl slices (stride 4096B), den=sum bf16(e),
//     rinv -> rbuf[w]. barrier.
//   step 3: RMW-normalize own Pl slice (8 slots: unpack, *rinv, repack).
//   step 4: pfr reads (ch=(kc*4+u)^(v&7)) + 32 PV MFMA, vt inline from L2.
// Same-wave ds ordering makes steps 3->4 safe without a barrier; cross-wave
// reads of Pl[w] happen only between the two barriers.
// LDS: Pl 32K + rbuf 8K = 40KB -> 2 blocks/CU (16 waves). VGPR ~125 (cap 128).
__global__ __launch_bounds__(512, 4) void fused_attn(
    const __bf16* __restrict__ qp, const __bf16* __restrict__ kp,
    const __bf16* __restrict__ vt, float* __restrict__ ctxp)
{
    __shared__ __bf16 Pl[8][32][64];   // 32 KB  bf16(e) / P tiles, swizzled
    __shared__ f32x4 rbuf[8][64];      // 8 KB   rinv per group [group][lane]

    const int tid  = threadIdx.x;
    const int w    = tid >> 6;          // wave == head
    const int lane = tid & 63;
    const int u = lane >> 4, v = lane & 15;

    const int bid = blockIdx.x;
    const int kh  = bid & 1;            // k-half
    const int b   = (bid >> 1) & 3;
    const int qt  = bid >> 3;
    const int q0  = qt * 32;
    const int h   = w;

    const __bf16* Qb = qp + ((long)b * 2048 + q0) * 1024 + h * 128;
    const __bf16* Kb = kp + (long)b * 2048 * 1024 + h * 128;
    const __bf16* Vb = vt + (long)(b * 8 + h) * 128 * 2048;
    float*        Cb = ctxp + (long)kh * 8388608
                            + ((long)b * 2048 + q0) * 1024 + h * 128;

    // Q fragments resident (32 VGPR)
    bf16x8 qf[2][4];
#pragma unroll
    for (int qj = 0; qj < 2; ++qj)
#pragma unroll
        for (int kk = 0; kk < 4; ++kk)
            qf[qj][kk] = *(const bf16x8*)&Qb[(long)(qj * 16 + v) * 1024 + kk * 32 + u * 8];

    f32x4 ctxa[8][2];
#pragma unroll
    for (int dt = 0; dt < 8; ++dt)
#pragma unroll
        for (int qj = 0; qj < 2; ++qj) ctxa[dt][qj] = (f32x4){0.f, 0.f, 0.f, 0.f};

    // reduce-read base: group w = (ki_w = w>>1, qj_w = w&1); this thread's
    // (k = ki_w*16+u*4+r, q = qj_w*16+v) slot inside a wave's Pl slice.
    const int kiw = w >> 1, qjw = w & 1;
    const char* redbase = (const char*)&Pl[0][qjw * 16 + v][0]
                        + (((kiw * 2 + (u >> 1)) ^ (v & 7)) * 16) + (u & 1) * 8;
    char* PlwBase = (char*)&Pl[w][0][0];
    const int swz = (v & 7) * 16;       // chunk-swizzle byte XOR for this lane

    const int ktbase = kh * 1024;
    for (int it = 0; it < 16; ++it) {
        const int kt = ktbase + it * 64;

        // ---- step 1: QK per ki, exp, pack unnormalized bf16(e) into Pl ----
#pragma unroll
        for (int ki = 0; ki < 4; ++ki) {
            f32x4 e0 = (f32x4){0.f, 0.f, 0.f, 0.f};
            f32x4 e1 = (f32x4){0.f, 0.f, 0.f, 0.f};
#pragma unroll
            for (int kk = 0; kk < 4; ++kk) {
                bf16x8 kf = *(const bf16x8*)&Kb[(long)(kt + ki * 16 + v) * 1024
                                                + kk * 32 + u * 8];
                e0 = mfma16(kf, qf[0][kk], e0);
                e1 = mfma16(kf, qf[1][kk], e1);
            }
#pragma unroll
            for (int r = 0; r < 4; ++r) { e0[r] = __expf(e0[r]); e1[r] = __expf(e1[r]); }
            const int choff = ((ki * 2 + (u >> 1)) * 16) ^ swz;   // chunk byte
            u32x2 w0; w0.x = pk2(e0[0], e0[1]); w0.y = pk2(e0[2], e0[3]);
            u32x2 w1; w1.x = pk2(e1[0], e1[1]); w1.y = pk2(e1[2], e1[3]);
            *(u32x2*)(PlwBase + v * 128 + choff + (u & 1) * 8) = w0;
            *(u32x2*)(PlwBase + (16 + v) * 128 + choff + (u & 1) * 8) = w1;
        }
        __syncthreads();

        // ---- step 2: wave w reduces group w across all 8 waves' slices ----
        {
            f32x4 den = (f32x4){0.f, 0.f, 0.f, 0.f};
#pragma unroll
            for (int wp = 0; wp < 8; ++wp) {
                u32x2 dw = *(const u32x2*)(redbase + wp * 4096);
                den[0] += bflo(dw.x); den[1] += bfhi(dw.x);
                den[2] += bflo(dw.y); den[3] += bfhi(dw.y);
            }
            f32x4 rv;
#pragma unroll
            for (int r = 0; r < 4; ++r) rv[r] = 1.0f / den[r];
            rbuf[w][lane] = rv;
        }
        __syncthreads();

        // ---- step 3: RMW-normalize own Pl slice in place ----
#pragma unroll
        for (int ki = 0; ki < 4; ++ki) {
            const int choff = ((ki * 2 + (u >> 1)) * 16) ^ swz;
#pragma unroll
            for (int qj = 0; qj < 2; ++qj) {
                f32x4 rr = rbuf[ki * 2 + qj][lane];
                char* p = PlwBase + (qj * 16 + v) * 128 + choff + (u & 1) * 8;
                u32x2 dw = *(u32x2*)p;
                dw.x = pk2(bflo(dw.x) * rr[0], bfhi(dw.x) * rr[1]);
                dw.y = pk2(bflo(dw.y) * rr[2], bfhi(dw.y) * rr[3]);
                *(u32x2*)p = dw;
            }
        }

        // ---- step 4: pfr reads + PV (same-wave ds ordering, no barrier) ----
        bf16x8 pfr[2][2];
#pragma unroll
        for (int kc = 0; kc < 2; ++kc)
#pragma unroll
            for (int qj = 0; qj < 2; ++qj)
                pfr[kc][qj] = *(const bf16x8*)(PlwBase + (qj * 16 + v) * 128
                                               + (((kc * 4 + u) * 16) ^ swz));
        __builtin_amdgcn_s_setprio(1);
#pragma unroll
        for (int dt = 0; dt < 8; ++dt) {
            bf16x8 vf0 = *(const bf16x8*)&Vb[(long)(dt * 16 + v) * 2048 + kt + u * 8];
            ctxa[dt][0] = mfma16(vf0, pfr[0][0], ctxa[dt][0]);
            ctxa[dt][1] = mfma16(vf0, pfr[0][1], ctxa[dt][1]);
            bf16x8 vf1 = *(const bf16x8*)&Vb[(long)(dt * 16 + v) * 2048 + kt + 32 + u * 8];
            ctxa[dt][0] = mfma16(vf1, pfr[1][0], ctxa[dt][0]);
            ctxa[dt][1] = mfma16(vf1, pfr[1][1], ctxa[dt][1]);
        }
        __builtin_amdgcn_s_setprio(0);
    }

    // ---- epilogue: f32 partial, concat layout [b][q][h*128+dh] ----
#pragma unroll
    for (int dt = 0; dt < 8; ++dt)
#pragma unroll
        for (int qj = 0; qj < 2; ++qj)
            *(f32x4*)&Cb[(long)(qj * 16 + v) * 1024 + dt * 16 + u * 4] = ctxa[dt][qj];
}

// ---------------------------------------------------------------------------
// out[8192,1024] f32 = (A0+A1)[8192,1024]f32 * Bt[1024,1024]^T (bf16 weights)
// A-staging fuses the partial-sum add + bf16 cast. XCD row-panel remap.
__global__ __launch_bounds__(256, 2) void gemm_wo(
    const float* __restrict__ A0, const float* __restrict__ A1,
    const __bf16* __restrict__ Bt, float* __restrict__ out)
{
    __shared__ __bf16 As[128 * 32];
    __shared__ __bf16 Bs[128 * 32];
    const int tid  = threadIdx.x;
    const int lane = tid & 63;
    const int u = lane >> 4, v = lane & 15;
    const int w = tid >> 6;
    const int wm = (w >> 1) * 64, wn = (w & 1) * 64;
    const int bid = blockIdx.y * 8 + blockIdx.x;
    const long tM = (long)(bid & 63) * 128;
    const int  tN = (bid >> 6) * 128;

    f32x4 acc[4][4];
#pragma unroll
    for (int i = 0; i < 4; ++i)
#pragma unroll
        for (int j = 0; j < 4; ++j) acc[i][j] = (f32x4){0.f, 0.f, 0.f, 0.f};

    const int ar0 = tid >> 2, ak0 = (tid & 3) * 8;
    const int ar1 = ar0 + 64;

    const float*  a0 = A0 + tM * 1024;
    const float*  a1 = A1 + tM * 1024;
    const __bf16* Bb = Bt + (long)tN * 1024;

    for (int k0 = 0; k0 < 1024; k0 += 32) {
        __syncthreads();
        {
            const float* p0 = a0 + (long)ar0 * 1024 + k0 + ak0;
            const float* p1 = a1 + (long)ar0 * 1024 + k0 + ak0;
            float4 x0 = *(const float4*)p0, x1 = *(const float4*)(p0 + 4);
            float4 y0 = *(const float4*)p1, y1 = *(const float4*)(p1 + 4);
            bf16x8 o;
            o[0] = (__bf16)(x0.x + y0.x); o[1] = (__bf16)(x0.y + y0.y);
            o[2] = (__bf16)(x0.z + y0.z); o[3] = (__bf16)(x0.w + y0.w);
            o[4] = (__bf16)(x1.x + y1.x); o[5] = (__bf16)(x1.y + y1.y);
            o[6] = (__bf16)(x1.z + y1.z); o[7] = (__bf16)(x1.w + y1.w);
            *(bf16x8*)&As[ar0 * 32 + ak0] = o;
            const float* q0p = a0 + (long)ar1 * 1024 + k0 + ak0;
            const float* q1p = a1 + (long)ar1 * 1024 + k0 + ak0;
            float4 z0 = *(const float4*)q0p, z1 = *(const float4*)(q0p + 4);
            float4 t0 = *(const float4*)q1p, t1 = *(const float4*)(q1p + 4);
            bf16x8 o2;
            o2[0] = (__bf16)(z0.x + t0.x); o2[1] = (__bf16)(z0.y + t0.y);
            o2[2] = (__bf16)(z0.z + t0.z); o2[3] = (__bf16)(z0.w + t0.w);
            o2[4] = (__bf16)(z1.x + t1.x); o2[5] = (__bf16)(z1.y + t1.y);
            o2[6] = (__bf16)(z1.z + t1.z); o2[7] = (__bf16)(z1.w + t1.w);
            *(bf16x8*)&As[ar1 * 32 + ak0] = o2;
        }
        cp16(&Bs[ar0 * 32 + ak0], Bb + (long)ar0 * 1024 + k0 + ak0);
        cp16(&Bs[ar1 * 32 + ak0], Bb + (long)ar1 * 1024 + k0 + ak0);
        __syncthreads();

        bf16x8 af[4], bfr[4];
#pragma unroll
        for (int i = 0; i < 4; ++i)
            af[i] = *(const bf16x8*)&As[(wm + i * 16 + v) * 32 + u * 8];
#pragma unroll
        for (int j = 0; j < 4; ++j)
            bfr[j] = *(const bf16x8*)&Bs[(wn + j * 16 + v) * 32 + u * 8];
#pragma unroll
        for (int i = 0; i < 4; ++i)
#pragma unroll
            for (int j = 0; j < 4; ++j)
                acc[i][j] = mfma16(af[i], bfr[j], acc[i][j]);
    }

#pragma unroll
    for (int i = 0; i < 4; ++i) {
#pragma unroll
        for (int j = 0; j < 4; ++j) {
            const long row0 = tM + wm + i * 16 + u * 4;
            const int  col  = tN + wn + j * 16 + v;
#pragma unroll
            for (int r = 0; r < 4; ++r)
                out[(row0 + r) * 1024 + col] = acc[i][j][r];
        }
    }
}

// ---------------------------------------------------------------------------
extern "C" void kernel_launch(void* const* d_in, const int* in_sizes, int n_in,
                              void* d_out, int out_size, void* d_ws, size_t ws_size,
                              hipStream_t stream)
{
    const float* Q  = (const float*)d_in[0];
    const float* K  = (const float*)d_in[1];
    const float* V  = (const float*)d_in[2];
    const float* WQ = (const float*)d_in[3];
    const float* WK = (const float*)d_in[4];
    const float* WV = (const float*)d_in[5];
    const float* WO = (const float*)d_in[6];

    // workspace (bytes): 4x2MB weights + 3x16.8MB bf16 (qp,kp,vt)
    //                    + 2x33.6MB f32 ctx partials = 125.8 MB
    __bf16* ws = (__bf16*)d_ws;
    __bf16* wq = ws;
    __bf16* wk = wq + 1048576;
    __bf16* wv = wk + 1048576;
    __bf16* wo = wv + 1048576;
    __bf16* qp = wo + 1048576;
    __bf16* kp = qp + 8388608;
    __bf16* vt = kp + 8388608;
    float* ctxf = (float*)(vt + 8388608);    // 2 x 8388608 f32

    const float qscale = 0.08838834764831845f;   // 1/sqrt(128)

    cast4_f32_to_bf16<<<dim3(256, 4), 256, 0, stream>>>(
        WQ, wq, WK, wk, WV, wv, WO, wo, 262144);

    qkv_proj<<<dim3(8, 64, 3), 256, 0, stream>>>(
        Q, K, V, wq, wk, wv, qp, kp, vt, qscale);

    fused_attn<<<512, 512, 0, stream>>>(qp, kp, vt, ctxf);

    gemm_wo<<<dim3(8, 64), 256, 0, stream>>>(
        ctxf, ctxf + 8388608, wo, (float*)d_out);
}

// Round 6
// 531.921 us; speedup vs baseline: 1.0604x; 1.0069x over previous
//
#include <hip/hip_runtime.h>
#include <math.h>
#include <stdint.h>

// ---------------------------------------------------------------------------
// MultiHeadAttention, softmax over HEAD axis (dim=1), bf16 MFMA pipeline.
// B=4, S=2048, DIM=1024, H=8, DH=128.
//   qp = (Q WQ^T)*1/sqrt(128), kp = K WK^T   [b,s,1024] bf16
//   vt = (V WV^T)^T  [b,h,dh,s] bf16         (casts fused into GEMM staging)
//   fused_attn v9: softmax over heads -> den[q,k]=sum_h e_h[q,k] elementwise.
//     512 blocks (64 qt x 4 b x 2 k-halves), 8 waves = 8 heads, q-tile 32,
//     KT=128, 8 iters. LDS 64 KB (Pl only). Per iter:
//       step1: 8x(8 QK MFMA + fast exp + pack) -> own Pl slice; vf0 hoist.
//       bar; step2: wave w reduces groups {w, w+8} across all 8 slices AND
//       writes back NORMALIZED values (merged reduce+normalize; no rbuf,
//       no RMW pass); bar; step3: PV 64 MFMA in two kc-halves.
//     exp/rcp via raw v_exp_f32/v_rcp_f32 (precise ocml exp was ~20 VALU
//     inst each = the round-5 VALU bloat).
//     ctx f32 partials (per k-half), summed in the WO GEMM's A-staging.
// ---------------------------------------------------------------------------

typedef __attribute__((ext_vector_type(8))) __bf16 bf16x8;
typedef __attribute__((ext_vector_type(4))) __bf16 bf16x4;
typedef __attribute__((ext_vector_type(4))) float  f32x4;
typedef __attribute__((ext_vector_type(2))) unsigned int u32x2;

__device__ __forceinline__ f32x4 mfma16(bf16x8 a, bf16x8 b, f32x4 c) {
    return __builtin_amdgcn_mfma_f32_16x16x32_bf16(a, b, c, 0, 0, 0);
}

// async global->LDS, 16B per lane; LDS dest must be wave-uniform-base + lane*16
__device__ __forceinline__ void cp16(void* lds, const void* g) {
    __builtin_amdgcn_global_load_lds(
        (__attribute__((address_space(1))) void*)(void*)(const_cast<void*>(g)),
        (__attribute__((address_space(3))) void*)lds,
        16, 0, 0);
}

// fast exp/rcp: single HW transcendental (CDNA interlocks handle latency).
__device__ __forceinline__ float fexp(float x) {
    float r;
    asm("v_exp_f32 %0, %1" : "=v"(r) : "v"(x * 1.44269504088896341f));
    return r;
}
__device__ __forceinline__ float frcp(float x) {
    float r;
    asm("v_rcp_f32 %0, %1" : "=v"(r) : "v"(x));
    return r;
}

// pack two f32 into a dword of two bf16 (RNE via HW cvt)
__device__ __forceinline__ uint32_t pk2(float a, float b) {
    __bf16 x = (__bf16)a, y = (__bf16)b;
    unsigned short xa = __builtin_bit_cast(unsigned short, x);
    unsigned short yb = __builtin_bit_cast(unsigned short, y);
    return (uint32_t)xa | ((uint32_t)yb << 16);
}
__device__ __forceinline__ float bflo(uint32_t d) {
    return __builtin_bit_cast(float, d << 16);
}
__device__ __forceinline__ float bfhi(uint32_t d) {
    return __builtin_bit_cast(float, d & 0xffff0000u);
}

// ---------------------------------------------------------------------------
// 4 weight tensors in one launch (bf16 for GEMM B-operands)
__global__ void cast4_f32_to_bf16(const float* __restrict__ s0, __bf16* __restrict__ d0,
                                  const float* __restrict__ s1, __bf16* __restrict__ d1,
                                  const float* __restrict__ s2, __bf16* __restrict__ d2,
                                  const float* __restrict__ s3, __bf16* __restrict__ d3,
                                  int n4) {
    const float* s = (blockIdx.y == 0) ? s0 : (blockIdx.y == 1) ? s1
                    : (blockIdx.y == 2) ? s2 : s3;
    __bf16* d = (blockIdx.y == 0) ? d0 : (blockIdx.y == 1) ? d1
               : (blockIdx.y == 2) ? d2 : d3;
    int i = blockIdx.x * blockDim.x + threadIdx.x;
    const int stride = gridDim.x * blockDim.x;
    for (; i < n4; i += stride) {
        float4 f = ((const float4*)s)[i];
        bf16x4 o;
        o[0] = (__bf16)f.x; o[1] = (__bf16)f.y; o[2] = (__bf16)f.z; o[3] = (__bf16)f.w;
        ((bf16x4*)d)[i] = o;
    }
}

// ---------------------------------------------------------------------------
// Batched Q/K/V projection with FUSED f32->bf16 cast in the A-staging.
// grid.z: 0 -> qp=(Q WQ^T)*qscale, 1 -> kp=K WK^T, 2 -> vt=(V WV^T)^T.
// XCD remap: consecutive dispatch ids take consecutive ROW panels.
__global__ __launch_bounds__(256, 2) void qkv_proj(
    const float* __restrict__ Qf, const float* __restrict__ Kf,
    const float* __restrict__ Vf,
    const __bf16* __restrict__ wq, const __bf16* __restrict__ wk,
    const __bf16* __restrict__ wv,
    __bf16* __restrict__ qp, __bf16* __restrict__ kp, __bf16* __restrict__ vtb,
    float qscale)
{
    __shared__ __bf16 As[128 * 32];
    __shared__ __bf16 Bs[128 * 32];
    const int z = blockIdx.z;
    const float*  Af = (z == 0) ? Qf : (z == 1) ? Kf : Vf;
    const __bf16* Bt = (z == 0) ? wq : (z == 1) ? wk : wv;
    __bf16* out      = (z == 0) ? qp : (z == 1) ? kp : vtb;
    const float scale = (z == 0) ? qscale : 1.0f;

    const int tid  = threadIdx.x;
    const int lane = tid & 63;
    const int u = lane >> 4, v = lane & 15;
    const int w = tid >> 6;
    const int wm = (w >> 1) * 64, wn = (w & 1) * 64;
    const int bid = blockIdx.y * 8 + blockIdx.x;
    const long tM = (long)(bid & 63) * 128;
    const int  tN = (bid >> 6) * 128;

    f32x4 acc[4][4];
#pragma unroll
    for (int i = 0; i < 4; ++i)
#pragma unroll
        for (int j = 0; j < 4; ++j) acc[i][j] = (f32x4){0.f, 0.f, 0.f, 0.f};

    const int ar0 = tid >> 2, ak0 = (tid & 3) * 8;
    const int ar1 = ar0 + 64;

    const float*  Ab = Af + tM * 1024;
    const __bf16* Bb = Bt + (long)tN * 1024;

    for (int k0 = 0; k0 < 1024; k0 += 32) {
        __syncthreads();
        // A: reg-staged f32 -> bf16 (fused cast)
        {
            const float* p = Ab + (long)ar0 * 1024 + k0 + ak0;
            float4 x0 = *(const float4*)p, x1 = *(const float4*)(p + 4);
            bf16x8 o;
            o[0] = (__bf16)x0.x; o[1] = (__bf16)x0.y; o[2] = (__bf16)x0.z; o[3] = (__bf16)x0.w;
            o[4] = (__bf16)x1.x; o[5] = (__bf16)x1.y; o[6] = (__bf16)x1.z; o[7] = (__bf16)x1.w;
            *(bf16x8*)&As[ar0 * 32 + ak0] = o;
            const float* q = Ab + (long)ar1 * 1024 + k0 + ak0;
            float4 y0 = *(const float4*)q, y1 = *(const float4*)(q + 4);
            bf16x8 o2;
            o2[0] = (__bf16)y0.x; o2[1] = (__bf16)y0.y; o2[2] = (__bf16)y0.z; o2[3] = (__bf16)y0.w;
            o2[4] = (__bf16)y1.x; o2[5] = (__bf16)y1.y; o2[6] = (__bf16)y1.z; o2[7] = (__bf16)y1.w;
            *(bf16x8*)&As[ar1 * 32 + ak0] = o2;
        }
        // B: async direct to LDS (bf16 weights)
        cp16(&Bs[ar0 * 32 + ak0], Bb + (long)ar0 * 1024 + k0 + ak0);
        cp16(&Bs[ar1 * 32 + ak0], Bb + (long)ar1 * 1024 + k0 + ak0);
        __syncthreads();

        bf16x8 af[4], bfr[4];
#pragma unroll
        for (int i = 0; i < 4; ++i)
            af[i] = *(const bf16x8*)&As[(wm + i * 16 + v) * 32 + u * 8];
#pragma unroll
        for (int j = 0; j < 4; ++j)
            bfr[j] = *(const bf16x8*)&Bs[(wn + j * 16 + v) * 32 + u * 8];
#pragma unroll
        for (int i = 0; i < 4; ++i)
#pragma unroll
            for (int j = 0; j < 4; ++j)
                acc[i][j] = mfma16(af[i], bfr[j], acc[i][j]);
    }

#pragma unroll
    for (int i = 0; i < 4; ++i) {
#pragma unroll
        for (int j = 0; j < 4; ++j) {
            const long row0 = tM + wm + i * 16 + u * 4;
            const int  col  = tN + wn + j * 16 + v;
            if (z < 2) {
#pragma unroll
                for (int r = 0; r < 4; ++r)
                    out[(row0 + r) * 1024 + col] = (__bf16)(acc[i][j][r] * scale);
            } else {
                const int bidx = (int)(row0 >> 11);
                const int s    = (int)(row0 & 2047);          // 4-aligned
                const int h = col >> 7, dh = col & 127;
                bf16x4 pkv;
#pragma unroll
                for (int r = 0; r < 4; ++r) pkv[r] = (__bf16)acc[i][j][r];
                *(bf16x4*)&out[((long)(bidx * 8 + h) * 128 + dh) * 2048 + s] = pkv;
            }
        }
    }
}

// ---------------------------------------------------------------------------
// fused_attn v9: QK^T -> head-softmax -> PV.
// 512 blocks: bid = qt*8 + b*2 + kh  (XCD = b*2+kh: K/V halves L2-resident).
// 512 threads = 8 waves, wave w == head. q-tile 32, KT=128, 8 iters.
//
// Pl element (k = ki*16 + kk8*8 + kk4*4 + r, q = qj*16 + vq) of wave slice w
// lives at byte: w*8192 + (qj*16+vq)*256 + ((ki*2+kk8)^(vq&7))*16 + kk4*8 + r*2.
//   step1 write (lane u,v; per ki): kk8=u>>1, kk4=u&1, rows v / 16+v.
//   step2 (merged): wave w owns groups g in {w, w+8}, g=(ki=g>>1, qj=g&1):
//     reads the group's 8B slot (kk8=u>>1, kk4=u&1, vq=v) from all 8 slices,
//     den = sum of bf16(e) in f32, rv = rcp(den), writes back normalized
//     bf16 pairs to the same 8 addresses. Disjoint slots across waves.
//   step3 PV: pfr chunk = (kc*4+u)^(v&7), two kc-halves to cap registers.
// LDS: Pl 64 KB only. launch_bounds (512,2): no spill (round-3 lesson).
__global__ __launch_bounds__(512, 2) void fused_attn(
    const __bf16* __restrict__ qp, const __bf16* __restrict__ kp,
    const __bf16* __restrict__ vt, float* __restrict__ ctxp)
{
    __shared__ __bf16 Pl[8][32][128];   // 64 KB; per-wave slice 8 KB

    const int tid  = threadIdx.x;
    const int w    = tid >> 6;          // wave == head
    const int lane = tid & 63;
    const int u = lane >> 4, v = lane & 15;

    const int bid = blockIdx.x;
    const int kh  = bid & 1;            // k-half
    const int b   = (bid >> 1) & 3;
    const int qt  = bid >> 3;
    const int q0  = qt * 32;
    const int h   = w;

    const __bf16* Qb = qp + ((long)b * 2048 + q0) * 1024 + h * 128;
    const __bf16* Kb = kp + (long)b * 2048 * 1024 + h * 128;
    const __bf16* Vb = vt + (long)(b * 8 + h) * 128 * 2048;
    float*        Cb = ctxp + (long)kh * 8388608
                            + ((long)b * 2048 + q0) * 1024 + h * 128;

    // Q fragments resident (32 VGPR)
    bf16x8 qf[2][4];
#pragma unroll
    for (int qj = 0; qj < 2; ++qj)
#pragma unroll
        for (int kk = 0; kk < 4; ++kk)
            qf[qj][kk] = *(const bf16x8*)&Qb[(long)(qj * 16 + v) * 1024 + kk * 32 + u * 8];

    f32x4 ctxa[8][2];
#pragma unroll
    for (int dt = 0; dt < 8; ++dt)
#pragma unroll
        for (int qj = 0; qj < 2; ++qj) ctxa[dt][qj] = (f32x4){0.f, 0.f, 0.f, 0.f};

    char* PlwBase = (char*)&Pl[w][0][0];
    const char* Pl0 = (const char*)&Pl[0][0][0];
    const int swz = v & 7;

    // merged-reduce slot offsets for this wave's two groups (g = w, w+8)
    const int off_g0 = ((w & 1) * 16 + v) * 256
                     + ((((w >> 1) * 2 + (u >> 1)) ^ swz) * 16) + (u & 1) * 8;
    const int off_g1 = ((w & 1) * 16 + v) * 256
                     + (((((w >> 1) + 4) * 2 + (u >> 1)) ^ swz) * 16) + (u & 1) * 8;

    const int ktbase = kh * 1024;
    for (int it = 0; it < 8; ++it) {
        const int kt = ktbase + it * 128;

        // ---- step 1: QK per ki (8x), fast exp, pack into own Pl slice ----
#pragma unroll
        for (int ki = 0; ki < 8; ++ki) {
            f32x4 e0 = (f32x4){0.f, 0.f, 0.f, 0.f};
            f32x4 e1 = (f32x4){0.f, 0.f, 0.f, 0.f};
#pragma unroll
            for (int kk = 0; kk < 4; ++kk) {
                bf16x8 kf = *(const bf16x8*)&Kb[(long)(kt + ki * 16 + v) * 1024
                                                + kk * 32 + u * 8];
                e0 = mfma16(kf, qf[0][kk], e0);
                e1 = mfma16(kf, qf[1][kk], e1);
            }
#pragma unroll
            for (int r = 0; r < 4; ++r) { e0[r] = fexp(e0[r]); e1[r] = fexp(e1[r]); }
            const int choff = (((ki * 2 + (u >> 1)) ^ swz) * 16) + (u & 1) * 8;
            u32x2 w0; w0.x = pk2(e0[0], e0[1]); w0.y = pk2(e0[2], e0[3]);
            u32x2 w1; w1.x = pk2(e1[0], e1[1]); w1.y = pk2(e1[2], e1[3]);
            *(u32x2*)(PlwBase + v * 256 + choff) = w0;
            *(u32x2*)(PlwBase + (16 + v) * 256 + choff) = w1;
        }

        // hoist PV half-0 kc=0 vt loads across the barriers (32 VGPR)
        bf16x8 vf0[8];
#pragma unroll
        for (int dt = 0; dt < 8; ++dt)
            vf0[dt] = *(const bf16x8*)&Vb[(long)(dt * 16 + v) * 2048 + kt + u * 8];

        __syncthreads();

        // ---- step 2: merged reduce + normalize-writeback, groups {w, w+8} ----
#pragma unroll
        for (int gp = 0; gp < 2; ++gp) {
            const int off = gp ? off_g1 : off_g0;
            u32x2 dw[8];
#pragma unroll
            for (int wp = 0; wp < 8; ++wp)
                dw[wp] = *(const u32x2*)(Pl0 + wp * 8192 + off);
            f32x4 den = (f32x4){0.f, 0.f, 0.f, 0.f};
#pragma unroll
            for (int wp = 0; wp < 8; ++wp) {
                den[0] += bflo(dw[wp].x); den[1] += bfhi(dw[wp].x);
                den[2] += bflo(dw[wp].y); den[3] += bfhi(dw[wp].y);
            }
            f32x4 rv;
#pragma unroll
            for (int r = 0; r < 4; ++r) rv[r] = frcp(den[r]);
#pragma unroll
            for (int wp = 0; wp < 8; ++wp) {
                u32x2 nw;
                nw.x = pk2(bflo(dw[wp].x) * rv[0], bfhi(dw[wp].x) * rv[1]);
                nw.y = pk2(bflo(dw[wp].y) * rv[2], bfhi(dw[wp].y) * rv[3]);
                *(u32x2*)(const_cast<char*>(Pl0) + wp * 8192 + off) = nw;
            }
        }
        __syncthreads();

        // ---- step 3: PV, two kc-halves (pfr capped at 16 VGPR live) ----
#pragma unroll
        for (int half = 0; half < 2; ++half) {
            bf16x8 pfr[2][2];
#pragma unroll
            for (int c = 0; c < 2; ++c)
#pragma unroll
                for (int qj = 0; qj < 2; ++qj) {
                    const int kc = half * 2 + c;
                    pfr[c][qj] = *(const bf16x8*)(PlwBase + (qj * 16 + v) * 256
                                                  + (((kc * 4 + u) ^ swz) * 16));
                }
            const int kofs = kt + half * 64;
            __builtin_amdgcn_s_setprio(1);
#pragma unroll
            for (int dt = 0; dt < 8; ++dt) {
                bf16x8 va = (half == 0) ? vf0[dt]
                          : *(const bf16x8*)&Vb[(long)(dt * 16 + v) * 2048 + kofs + u * 8];
                ctxa[dt][0] = mfma16(va, pfr[0][0], ctxa[dt][0]);
                ctxa[dt][1] = mfma16(va, pfr[0][1], ctxa[dt][1]);
                bf16x8 vb = *(const bf16x8*)&Vb[(long)(dt * 16 + v) * 2048 + kofs + 32 + u * 8];
                ctxa[dt][0] = mfma16(vb, pfr[1][0], ctxa[dt][0]);
                ctxa[dt][1] = mfma16(vb, pfr[1][1], ctxa[dt][1]);
            }
            __builtin_amdgcn_s_setprio(0);
        }
    }

    // ---- epilogue: f32 partial, concat layout [b][q][h*128+dh] ----
#pragma unroll
    for (int dt = 0; dt < 8; ++dt)
#pragma unroll
        for (int qj = 0; qj < 2; ++qj)
            *(f32x4*)&Cb[(long)(qj * 16 + v) * 1024 + dt * 16 + u * 4] = ctxa[dt][qj];
}

// ---------------------------------------------------------------------------
// out[8192,1024] f32 = (A0+A1)[8192,1024]f32 * Bt[1024,1024]^T (bf16 weights)
// A-staging fuses the partial-sum add + bf16 cast. XCD row-panel remap.
__global__ __launch_bounds__(256, 2) void gemm_wo(
    const float* __restrict__ A0, const float* __restrict__ A1,
    const __bf16* __restrict__ Bt, float* __restrict__ out)
{
    __shared__ __bf16 As[128 * 32];
    __shared__ __bf16 Bs[128 * 32];
    const int tid  = threadIdx.x;
    const int lane = tid & 63;
    const int u = lane >> 4, v = lane & 15;
    const int w = tid >> 6;
    const int wm = (w >> 1) * 64, wn = (w & 1) * 64;
    const int bid = blockIdx.y * 8 + blockIdx.x;
    const long tM = (long)(bid & 63) * 128;
    const int  tN = (bid >> 6) * 128;

    f32x4 acc[4][4];
#pragma unroll
    for (int i = 0; i < 4; ++i)
#pragma unroll
        for (int j = 0; j < 4; ++j) acc[i][j] = (f32x4){0.f, 0.f, 0.f, 0.f};

    const int ar0 = tid >> 2, ak0 = (tid & 3) * 8;
    const int ar1 = ar0 + 64;

    const float*  a0 = A0 + tM * 1024;
    const float*  a1 = A1 + tM * 1024;
    const __bf16* Bb = Bt + (long)tN * 1024;

    for (int k0 = 0; k0 < 1024; k0 += 32) {
        __syncthreads();
        {
            const float* p0 = a0 + (long)ar0 * 1024 + k0 + ak0;
            const float* p1 = a1 + (long)ar0 * 1024 + k0 + ak0;
            float4 x0 = *(const float4*)p0, x1 = *(const float4*)(p0 + 4);
            float4 y0 = *(const float4*)p1, y1 = *(const float4*)(p1 + 4);
            bf16x8 o;
            o[0] = (__bf16)(x0.x + y0.x); o[1] = (__bf16)(x0.y + y0.y);
            o[2] = (__bf16)(x0.z + y0.z); o[3] = (__bf16)(x0.w + y0.w);
            o[4] = (__bf16)(x1.x + y1.x); o[5] = (__bf16)(x1.y + y1.y);
            o[6] = (__bf16)(x1.z + y1.z); o[7] = (__bf16)(x1.w + y1.w);
            *(bf16x8*)&As[ar0 * 32 + ak0] = o;
            const float* q0p = a0 + (long)ar1 * 1024 + k0 + ak0;
            const float* q1p = a1 + (long)ar1 * 1024 + k0 + ak0;
            float4 z0 = *(const float4*)q0p, z1 = *(const float4*)(q0p + 4);
            float4 t0 = *(const float4*)q1p, t1 = *(const float4*)(q1p + 4);
            bf16x8 o2;
            o2[0] = (__bf16)(z0.x + t0.x); o2[1] = (__bf16)(z0.y + t0.y);
            o2[2] = (__bf16)(z0.z + t0.z); o2[3] = (__bf16)(z0.w + t0.w);
            o2[4] = (__bf16)(z1.x + t1.x); o2[5] = (__bf16)(z1.y + t1.y);
            o2[6] = (__bf16)(z1.z + t1.z); o2[7] = (__bf16)(z1.w + t1.w);
            *(bf16x8*)&As[ar1 * 32 + ak0] = o2;
        }
        cp16(&Bs[ar0 * 32 + ak0], Bb + (long)ar0 * 1024 + k0 + ak0);
        cp16(&Bs[ar1 * 32 + ak0], Bb + (long)ar1 * 1024 + k0 + ak0);
        __syncthreads();

        bf16x8 af[4], bfr[4];
#pragma unroll
        for (int i = 0; i < 4; ++i)
            af[i] = *(const bf16x8*)&As[(wm + i * 16 + v) * 32 + u * 8];
#pragma unroll
        for (int j = 0; j < 4; ++j)
            bfr[j] = *(const bf16x8*)&Bs[(wn + j * 16 + v) * 32 + u * 8];
#pragma unroll
        for (int i = 0; i < 4; ++i)
#pragma unroll
            for (int j = 0; j < 4; ++j)
                acc[i][j] = mfma16(af[i], bfr[j], acc[i][j]);
    }

#pragma unroll
    for (int i = 0; i < 4; ++i) {
#pragma unroll
        for (int j = 0; j < 4; ++j) {
            const long row0 = tM + wm + i * 16 + u * 4;
            const int  col  = tN + wn + j * 16 + v;
#pragma unroll
            for (int r = 0; r < 4; ++r)
                out[(row0 + r) * 1024 + col] = acc[i][j][r];
        }
    }
}

// ---------------------------------------------------------------------------
extern "C" void kernel_launch(void* const* d_in, const int* in_sizes, int n_in,
                              void* d_out, int out_size, void* d_ws, size_t ws_size,
                              hipStream_t stream)
{
    const float* Q  = (const float*)d_in[0];
    const float* K  = (const float*)d_in[1];
    const float* V  = (const float*)d_in[2];
    const float* WQ = (const float*)d_in[3];
    const float* WK = (const float*)d_in[4];
    const float* WV = (const float*)d_in[5];
    const float* WO = (const float*)d_in[6];

    // workspace (bytes): 4x2MB weights + 3x16.8MB bf16 (qp,kp,vt)
    //                    + 2x33.6MB f32 ctx partials = 125.8 MB
    __bf16* ws = (__bf16*)d_ws;
    __bf16* wq = ws;
    __bf16* wk = wq + 1048576;
    __bf16* wv = wk + 1048576;
    __bf16* wo = wv + 1048576;
    __bf16* qp = wo + 1048576;
    __bf16* kp = qp + 8388608;
    __bf16* vt = kp + 8388608;
    float* ctxf = (float*)(vt + 8388608);    // 2 x 8388608 f32

    const float qscale = 0.08838834764831845f;   // 1/sqrt(128)

    cast4_f32_to_bf16<<<dim3(256, 4), 256, 0, stream>>>(
        WQ, wq, WK, wk, WV, wv, WO, wo, 262144);

    qkv_proj<<<dim3(8, 64, 3), 256, 0, stream>>>(
        Q, K, V, wq, wk, wv, qp, kp, vt, qscale);

    fused_attn<<<512, 512, 0, stream>>>(qp, kp, vt, ctxf);

    gemm_wo<<<dim3(8, 64), 256, 0, stream>>>(
        ctxf, ctxf + 8388608, wo, (float*)d_out);
}